// Round 4
// baseline (368.492 us; speedup 1.0000x reference)
//
#include <hip/hip_runtime.h>
#include <hip/hip_bf16.h>
#include <stdint.h>

// Problem constants (fixed by reference: B=8, Q=4096, E=1024, M=256)
#define TOK 32768
#define EMB 1024
#define MSL 256

typedef __attribute__((ext_vector_type(8))) short short8;   // 8 bf16 = 4 VGPRs (MFMA A/B frag)
typedef __attribute__((ext_vector_type(4))) float f32x4;    // MFMA C/D frag

// raw barrier: lgkm drain only (publishes ds_writes). No vmcnt drain — the
// fused kernel has NO cross-wave global->LDS dependencies.
#define SBAR() asm volatile("s_waitcnt lgkmcnt(0)\n\ts_barrier" ::: "memory")

__device__ __forceinline__ ushort f2bf(float f) {
    union { float f; uint32_t u; } c; c.f = f;
    uint32_t u = c.u;
    return (ushort)((u + 0x7fffu + ((u >> 16) & 1u)) >> 16);  // RNE
}

// truncation split: f = hi + lo with |f - hi - lo| <= 2^-16 |f|
__device__ __forceinline__ void split2(float f, ushort& h, ushort& l) {
    union { float f; uint32_t u; } c; c.f = f;
    h = (ushort)(c.u >> 16);
    union { uint32_t u; float f; } hv; hv.u = c.u & 0xffff0000u;
    union { float f; uint32_t u; } lc; lc.f = f - hv.f;
    l = (ushort)(lc.u >> 16);
}

__device__ __forceinline__ void async_copy16(const void* gsrc, void* ldst) {
    __builtin_amdgcn_global_load_lds(
        (const __attribute__((address_space(1))) uint32_t*)gsrc,
        (__attribute__((address_space(3))) uint32_t*)ldst,
        16, 0, 0);
}

// Fragment-order index for phase-1 B operands (Ph/Pl), element (m, k):
//   kt=k>>6, kc=(k>>3)&7, ks=kc>>2, lanehi=kc&3, e=k&7, wcj=m>>4, lanelo=m&15
//   idx = (((kt*2+ks)*16 + wcj)*64 + lanehi*16+lanelo)*8 + e
// A wave (wc) reading (kt,ks,j) loads 64 lanes x 16B contiguous.

// =====================================================================
// pre_small: merged tiny precomputes
// =====================================================================
__global__ __launch_bounds__(256) void pre_small(
    const float* __restrict__ Wq, ushort* __restrict__ wqth, ushort* __restrict__ wqtl,
    const float* __restrict__ mb, ushort* __restrict__ mbh, ushort* __restrict__ mbl,
    const float* __restrict__ bq, float* __restrict__ cvec)
{
    __shared__ float ld[64 * 65];
    const int b = blockIdx.x;
    const int t = threadIdx.x;
    if (b < 256) {
        const int eBase = (b & 15) * 64;
        const int fBase = (b >> 4) * 64;
        #pragma unroll
        for (int r = 0; r < 16; ++r) {
            int row = r * 4 + (t >> 6);      // f within tile
            int col = t & 63;                // e within tile
            ld[row * 65 + col] = Wq[(size_t)(fBase + row) * EMB + eBase + col];
        }
        __syncthreads();
        #pragma unroll
        for (int r = 0; r < 16; ++r) {
            int row = r * 4 + (t >> 6);      // e within tile
            int col = t & 63;                // f within tile
            float v = ld[col * 65 + row];    // = Wq[fBase+col][eBase+row]
            ushort h, l; split2(v, h, l);
            size_t o = (size_t)(eBase + row) * EMB + fBase + col;
            wqth[o] = h; wqtl[o] = l;
        }
    } else if (b < 512) {
        int i = (b - 256) * 256 + t;         // mb: 256*1024/4 float4s
        float4 v = ((const float4*)mb)[i];
        ushort4 h4, l4;
        split2(v.x, h4.x, l4.x); split2(v.y, h4.y, l4.y);
        split2(v.z, h4.z, l4.z); split2(v.w, h4.w, l4.w);
        ((ushort4*)mbh)[i] = h4;
        ((ushort4*)mbl)[i] = l4;
    } else {
        int m = (b - 512) * 4 + (t >> 6);
        int lane = t & 63;
        const float4* mrow = (const float4*)(mb + (size_t)m * EMB);
        const float4* brow = (const float4*)bq;
        float s = 0.f;
        #pragma unroll
        for (int k = 0; k < 4; ++k) {
            float4 a = mrow[lane + k * 64];
            float4 bb = brow[lane + k * 64];
            s += a.x * bb.x + a.y * bb.y + a.z * bb.z + a.w * bb.w;
        }
        #pragma unroll
        for (int off = 32; off; off >>= 1) s += __shfl_xor(s, off, 64);
        if (lane == 0) cvec[m] = s;
    }
}

// =====================================================================
// Split-precision GEMM body (prologue GEMMs).
// MODE 0: P GEMM -> write hi/lo into phase-1 FRAGMENT layout (O1=Pfh, O2=Pfl)
// MODE 1: RT GEMM -> write bf16 into phase-2 fragment layout (O1=RTfrag)
// =====================================================================
template<int MODE>
__device__ __forceinline__ void gemm_body(
    ushort* smem, const float* __restrict__ A,
    const ushort* __restrict__ Bh, const ushort* __restrict__ Bl,
    ushort* __restrict__ O1, ushort* __restrict__ O2,
    int K, int bx, int by)
{
    ushort* sAh = smem;            // [128][64] = 8192 ushorts each
    ushort* sAl = smem + 8192;
    ushort* sBh = smem + 16384;
    ushort* sBl = smem + 24576;

    const int t = threadIdx.x;
    const int lane = t & 63;
    const int wave = t >> 6;
    const int wr = wave >> 1;
    const int wc = wave & 1;
    const int rowBase = by * 128;
    const int colBase = bx * 128;

    const float*  Ab  = A  + (size_t)rowBase * K;
    const ushort* Bhb = Bh + (size_t)colBase * K;
    const ushort* Blb = Bl + (size_t)colBase * K;

    const int cg = ((t & 7) ^ ((t >> 3) & 7)) << 3;

    f32x4 acc[4][4] = {};

    const int kIters = K >> 6;
    for (int kt = 0; kt < kIters; ++kt) {
        const int k0 = kt << 6;
        __syncthreads();
        #pragma unroll
        for (int r = 0; r < 4; ++r) {
            int row = r * 32 + (t >> 3);
            async_copy16(Bhb + (size_t)row * K + k0 + cg, &sBh[(size_t)(r * 256 + wave * 64) * 8]);
            async_copy16(Blb + (size_t)row * K + k0 + cg, &sBl[(size_t)(r * 256 + wave * 64) * 8]);
        }
        #pragma unroll
        for (int r = 0; r < 4; ++r) {
            int i = r * 256 + t;
            int row = r * 32 + (t >> 3);
            const float* src = Ab + (size_t)row * K + k0 + cg;
            float4 f0 = *(const float4*)src;
            float4 f1 = *(const float4*)(src + 4);
            short8 hv, lv; ushort h, l;
            split2(f0.x, h, l); hv[0] = (short)h; lv[0] = (short)l;
            split2(f0.y, h, l); hv[1] = (short)h; lv[1] = (short)l;
            split2(f0.z, h, l); hv[2] = (short)h; lv[2] = (short)l;
            split2(f0.w, h, l); hv[3] = (short)h; lv[3] = (short)l;
            split2(f1.x, h, l); hv[4] = (short)h; lv[4] = (short)l;
            split2(f1.y, h, l); hv[5] = (short)h; lv[5] = (short)l;
            split2(f1.z, h, l); hv[6] = (short)h; lv[6] = (short)l;
            split2(f1.w, h, l); hv[7] = (short)h; lv[7] = (short)l;
            *(short8*)&sAh[(size_t)i * 8] = hv;
            *(short8*)&sAl[(size_t)i * 8] = lv;
        }
        __syncthreads();

        #pragma unroll
        for (int ks = 0; ks < 2; ++ks) {
            const int kc = ks * 4 + (lane >> 4);
            short8 ah[4], al[4], bh[4], bl[4];
            #pragma unroll
            for (int i2 = 0; i2 < 4; ++i2) {
                int row = wr * 64 + i2 * 16 + (lane & 15);
                int off = row * 64 + ((kc ^ (row & 7)) << 3);
                ah[i2] = *(const short8*)&sAh[off];
                al[i2] = *(const short8*)&sAl[off];
            }
            #pragma unroll
            for (int j = 0; j < 4; ++j) {
                int row = wc * 64 + j * 16 + (lane & 15);
                int off = row * 64 + ((kc ^ (row & 7)) << 3);
                bh[j] = *(const short8*)&sBh[off];
                bl[j] = *(const short8*)&sBl[off];
            }
            #pragma unroll
            for (int i2 = 0; i2 < 4; ++i2)
                #pragma unroll
                for (int j = 0; j < 4; ++j) {
                    acc[i2][j] = __builtin_amdgcn_mfma_f32_16x16x32_bf16(ah[i2], bh[j], acc[i2][j], 0, 0, 0);
                    acc[i2][j] = __builtin_amdgcn_mfma_f32_16x16x32_bf16(ah[i2], bl[j], acc[i2][j], 0, 0, 0);
                    acc[i2][j] = __builtin_amdgcn_mfma_f32_16x16x32_bf16(al[i2], bh[j], acc[i2][j], 0, 0, 0);
                }
        }
    }

    // epilogue: C/D layout col=lane&15, row=(lane>>4)*4+reg  [verified m89/m91]
    #pragma unroll
    for (int i2 = 0; i2 < 4; ++i2) {
        #pragma unroll
        for (int j = 0; j < 4; ++j) {
            const int col = colBase + wc * 64 + j * 16 + (lane & 15);
            #pragma unroll
            for (int r = 0; r < 4; ++r) {
                const int row = rowBase + wr * 64 + i2 * 16 + ((lane >> 4) << 2) + r;
                float v = acc[i2][j][r];
                if (MODE == 0) {
                    // (m=row, k=col) -> phase-1 fragment index
                    int ktx = col >> 6, kcc = (col >> 3) & 7;
                    int ksx = kcc >> 2, lh = kcc & 3, e = col & 7;
                    int wcj = row >> 4, ll = row & 15;
                    size_t idx = (((size_t)(ktx * 2 + ksx) * 16 + wcj) * 64 + lh * 16 + ll) * 8 + e;
                    ushort h, l; split2(v, h, l);
                    O1[idx] = h;
                    O2[idx] = l;
                } else {
                    // (f=row, m=col) -> phase-2 fragment index
                    int fc = row >> 6, jj = (row & 63) >> 4, lanelo = row & 15;
                    int cc = col >> 3, ksx = cc >> 2, lanehi = cc & 3, e = col & 7;
                    size_t idx = ((((size_t)fc * 8 + ksx) * 4 + jj) * 64 + lanehi * 16 + lanelo) * 8 + e;
                    O1[idx] = f2bf(v);
                }
            }
        }
    }
}

// pre_gemms: blocks 0..15 -> P frag hi/lo; blocks 16..31 -> RT frag layout
__global__ __launch_bounds__(256) void pre_gemms(
    const float* __restrict__ mb, const ushort* __restrict__ wqth, const ushort* __restrict__ wqtl,
    const float* __restrict__ Wo, const ushort* __restrict__ mbh, const ushort* __restrict__ mbl,
    ushort* __restrict__ Pfh, ushort* __restrict__ Pfl, ushort* __restrict__ RTfrag)
{
    __shared__ ushort smem[32768];   // 64 KiB
    const int b = blockIdx.x;
    if (b < 16) {
        // P[m,e] = sum_f mb[m,f] * WqT[e,f] ; grid (8 e-cols x 2 m-rows)
        gemm_body<0>(smem, mb, wqth, wqtl, Pfh, Pfl, EMB, b & 7, b >> 3);
    } else {
        // RT[f,m] = sum_e Wo[f,e] * mb[m,e] ; grid (2 m-cols x 8 f-rows)
        const int id = b - 16;
        gemm_body<1>(smem, Wo, mbh, mbl, RTfrag, nullptr, EMB, id & 1, id >> 1);
    }
}

// =====================================================================
// Fused: scores + softmax + PV + bias + residual. 64 tokens/block,
// 256 threads = 4 waves, ~34 KiB LDS -> 3 blocks/CU (12 waves/CU):
// the m97/m114 cross-block overlap mechanism.
//
// Phase 1: scores[64x256] = x @ (Ph+Pl)^T + c.  B-operands come DIRECTLY
// from global in MFMA-fragment order (Pfh/Pfl, L2/L3-resident 1 MB) --
// no LDS staging, no global_load_lds, no vmcnt coupling. Only x goes
// through LDS (split hi/lo once, read by all 4 waves), double-buffered ->
// ONE lgkm-only barrier per K-step.
// Softmax: 16-lane shfl groups + 4-way cross-wave combine (2 KB LDS).
// Phase 2: out = w @ RT^T + bo + x. Barrier-free, RT frags from global.
//
// LDS map (ushort idx): x dbuf 0..16383 (buf k&1: base (k&1)*8192,
//   sAh +0, sAl +4096); sW[64][256] overlays 0..16383 (post-phase-1);
//   redM/redS floats at 16384..17407.
// =====================================================================
__global__ __launch_bounds__(256, 3) void fused_attn(
    const float* __restrict__ x, const ushort* __restrict__ Pfh,
    const ushort* __restrict__ Pfl, const float* __restrict__ cvec,
    const ushort* __restrict__ RTfrag, const float* __restrict__ bo,
    float* __restrict__ out)
{
    __shared__ ushort smem[17408];            // 34 KiB
    ushort* sW  = smem;                       // [64][256] swizzled (phase 2)
    float*  redM = (float*)&smem[16384];      // [4][64] partial max
    float*  redS = (float*)&smem[16896];      // [4][64] partial sum

    const int t = threadIdx.x;
    const int lane = t & 63;
    const int wave = t >> 6;                  // 0..3
    const int wc = wave;                      // phase-1 col group (64 m each)
    const int rowBase = blockIdx.x * 64;

    const float* Ab = x + (size_t)rowBase * EMB;
    const int cg = ((t & 7) ^ ((t >> 3) & 7)) << 3;

    f32x4 acc[4][4] = {};
    float4 xr[2][2];

    // prefetch x slice for kt into registers (4 float4)
    auto loadX = [&](int kt) {
        const int k0 = kt << 6;
        #pragma unroll
        for (int r = 0; r < 2; ++r) {
            const float* src = Ab + (size_t)(r * 32 + (t >> 3)) * EMB + k0 + cg;
            xr[r][0] = *(const float4*)src;
            xr[r][1] = *(const float4*)(src + 4);
        }
    };

    loadX(0);

    // ---------------- phase 1: scores ----------------
    for (int kt = 0; kt < 16; ++kt) {
        ushort* bufAh = smem + (kt & 1) * 8192;
        ushort* bufAl = bufAh + 4096;
        // split x(kt) regs -> LDS (hi/lo)
        #pragma unroll
        for (int r = 0; r < 2; ++r) {
            int i = r * 256 + t;
            short8 hv, lv; ushort h, l;
            split2(xr[r][0].x, h, l); hv[0] = (short)h; lv[0] = (short)l;
            split2(xr[r][0].y, h, l); hv[1] = (short)h; lv[1] = (short)l;
            split2(xr[r][0].z, h, l); hv[2] = (short)h; lv[2] = (short)l;
            split2(xr[r][0].w, h, l); hv[3] = (short)h; lv[3] = (short)l;
            split2(xr[r][1].x, h, l); hv[4] = (short)h; lv[4] = (short)l;
            split2(xr[r][1].y, h, l); hv[5] = (short)h; lv[5] = (short)l;
            split2(xr[r][1].z, h, l); hv[6] = (short)h; lv[6] = (short)l;
            split2(xr[r][1].w, h, l); hv[7] = (short)h; lv[7] = (short)l;
            *(short8*)&bufAh[(size_t)i * 8] = hv;
            *(short8*)&bufAl[(size_t)i * 8] = lv;
        }
        if (kt < 15) loadX(kt + 1);   // prefetch next slice (covers HBM latency)
        SBAR();   // publish this buf; prev buf's reads were fenced 1 iter ago

        #pragma unroll
        for (int ks = 0; ks < 2; ++ks) {
            const int kc = ks * 4 + (lane >> 4);
            short8 ah[4], al[4], bh[4], bl[4];
            #pragma unroll
            for (int i2 = 0; i2 < 4; ++i2) {
                int row = i2 * 16 + (lane & 15);
                int off = row * 64 + ((kc ^ (row & 7)) << 3);
                ah[i2] = *(const short8*)&bufAh[off];
                al[i2] = *(const short8*)&bufAl[off];
            }
            #pragma unroll
            for (int j = 0; j < 4; ++j) {
                // B frags straight from global (fragment-order, L2-resident)
                size_t boff = ((size_t)((kt * 2 + ks) * 16 + wc * 4 + j) * 64 + lane) * 8;
                bh[j] = *(const short8*)&Pfh[boff];
                bl[j] = *(const short8*)&Pfl[boff];
            }
            #pragma unroll
            for (int i2 = 0; i2 < 4; ++i2)
                #pragma unroll
                for (int j = 0; j < 4; ++j) {
                    acc[i2][j] = __builtin_amdgcn_mfma_f32_16x16x32_bf16(ah[i2], bh[j], acc[i2][j], 0, 0, 0);
                    acc[i2][j] = __builtin_amdgcn_mfma_f32_16x16x32_bf16(ah[i2], bl[j], acc[i2][j], 0, 0, 0);
                    acc[i2][j] = __builtin_amdgcn_mfma_f32_16x16x32_bf16(al[i2], bh[j], acc[i2][j], 0, 0, 0);
                }
        }
    }

    // ---------------- softmax (64 rows; cols split over 4 waves) ------------
    {
        float cj[4];
        #pragma unroll
        for (int j = 0; j < 4; ++j) cj[j] = cvec[wc * 64 + j * 16 + (lane & 15)];
        #pragma unroll
        for (int i2 = 0; i2 < 4; ++i2)
            #pragma unroll
            for (int j = 0; j < 4; ++j)
                #pragma unroll
                for (int r = 0; r < 4; ++r) acc[i2][j][r] += cj[j];
    }
    float pmax[4][4];
    #pragma unroll
    for (int i2 = 0; i2 < 4; ++i2)
        #pragma unroll
        for (int r = 0; r < 4; ++r) {
            float m0 = fmaxf(fmaxf(acc[i2][0][r], acc[i2][1][r]),
                             fmaxf(acc[i2][2][r], acc[i2][3][r]));
            #pragma unroll
            for (int off = 8; off; off >>= 1) m0 = fmaxf(m0, __shfl_xor(m0, off, 64));
            pmax[i2][r] = m0;
        }
    __syncthreads();   // bar A: all phase-1 LDS reads complete
    if ((lane & 15) == 0) {
        #pragma unroll
        for (int i2 = 0; i2 < 4; ++i2)
            #pragma unroll
            for (int r = 0; r < 4; ++r)
                redM[wc * 64 + i2 * 16 + ((lane >> 4) << 2) + r] = pmax[i2][r];
    }
    __syncthreads();   // bar B
    {
        float psum[4][4];
        #pragma unroll
        for (int i2 = 0; i2 < 4; ++i2)
            #pragma unroll
            for (int r = 0; r < 4; ++r) {
                int R = i2 * 16 + ((lane >> 4) << 2) + r;
                float mx = fmaxf(fmaxf(redM[R], redM[64 + R]),
                                 fmaxf(redM[128 + R], redM[192 + R]));
                float s = 0.f;
                #pragma unroll
                for (int j = 0; j < 4; ++j) {
                    float e = __expf(acc[i2][j][r] - mx);
                    acc[i2][j][r] = e;
                    s += e;
                }
                #pragma unroll
                for (int off = 8; off; off >>= 1) s += __shfl_xor(s, off, 64);
                psum[i2][r] = s;
            }
        if ((lane & 15) == 0) {
            #pragma unroll
            for (int i2 = 0; i2 < 4; ++i2)
                #pragma unroll
                for (int r = 0; r < 4; ++r)
                    redS[wc * 64 + i2 * 16 + ((lane >> 4) << 2) + r] = psum[i2][r];
        }
    }
    __syncthreads();   // bar C
    // normalize -> bf16 weights -> swizzled sW[64][256]
    #pragma unroll
    for (int i2 = 0; i2 < 4; ++i2)
        #pragma unroll
        for (int r = 0; r < 4; ++r) {
            int R = i2 * 16 + ((lane >> 4) << 2) + r;
            float tot = redS[R] + redS[64 + R] + redS[128 + R] + redS[192 + R];
            float inv = 1.0f / tot;
            #pragma unroll
            for (int j = 0; j < 4; ++j) {
                int col = wc * 64 + j * 16 + (lane & 15);
                int cc = col >> 3;
                int slot = (cc & 24) | ((cc & 7) ^ (R & 7));
                sW[R * 256 + slot * 8 + (lane & 7)] = f2bf(acc[i2][j][r] * inv);
            }
        }
    __syncthreads();   // bar D: sW complete

    // ---------------- phase 2: out = w @ RT^T + bo + x (barrier-free) -------
    const int wr2 = wave >> 1;    // 0..1 : token rows wr2*32
    const int wc2 = wave & 1;     // 0..1 : f cols wc2*32 within a 64-f chunk

    short8 af[2][8];
    #pragma unroll
    for (int i2 = 0; i2 < 2; ++i2) {
        int R = wr2 * 32 + i2 * 16 + (lane & 15);
        #pragma unroll
        for (int ks = 0; ks < 8; ++ks) {
            int cc = ks * 4 + (lane >> 4);
            int slot = (cc & 24) | ((cc & 7) ^ (R & 7));
            af[i2][ks] = *(const short8*)&sW[R * 256 + slot * 8];
        }
    }

    for (int fc = 0; fc < 16; ++fc) {
        f32x4 acc2[2][2] = {};
        #pragma unroll
        for (int ks = 0; ks < 8; ++ks) {
            short8 b[2];
            #pragma unroll
            for (int j = 0; j < 2; ++j) {
                int jj = wc2 * 2 + j;
                b[j] = *(const short8*)&RTfrag[((((size_t)fc * 8 + ks) * 4 + jj) * 64 + lane) * 8];
            }
            #pragma unroll
            for (int i2 = 0; i2 < 2; ++i2)
                #pragma unroll
                for (int j = 0; j < 2; ++j)
                    acc2[i2][j] = __builtin_amdgcn_mfma_f32_16x16x32_bf16(
                        af[i2][ks], b[j], acc2[i2][j], 0, 0, 0);
        }
        // epilogue: + bias + residual, fp32 store (x rows L2/L3-hot from ph1)
        #pragma unroll
        for (int i2 = 0; i2 < 2; ++i2)
            #pragma unroll
            for (int j = 0; j < 2; ++j) {
                int col = fc * 64 + wc2 * 32 + j * 16 + (lane & 15);
                float bcol = bo[col];
                #pragma unroll
                for (int r = 0; r < 4; ++r) {
                    int row = rowBase + wr2 * 32 + i2 * 16 + ((lane >> 4) << 2) + r;
                    out[(size_t)row * EMB + col] =
                        acc2[i2][j][r] + bcol + x[(size_t)row * EMB + col];
                }
            }
    }
}

extern "C" void kernel_launch(void* const* d_in, const int* in_sizes, int n_in,
                              void* d_out, int out_size, void* d_ws, size_t ws_size,
                              hipStream_t stream) {
    const float* x  = (const float*)d_in[0];   // [TOK, EMB]
    const float* mb = (const float*)d_in[1];   // [MSL, EMB]
    const float* Wq = (const float*)d_in[2];   // [EMB, EMB]
    const float* bq = (const float*)d_in[3];   // [EMB]
    const float* Wo = (const float*)d_in[4];   // [EMB, EMB]
    const float* bo = (const float*)d_in[5];   // [EMB]
    float* out = (float*)d_out;                // [TOK, EMB]

    // workspace layout (~6.5 MB), no atomics -> no zeroing
    char* ws = (char*)d_ws;
    size_t o = 0;
    ushort* mbh    = (ushort*)(ws + o); o += (size_t)MSL * EMB * 2;   // mb hi
    ushort* mbl    = (ushort*)(ws + o); o += (size_t)MSL * EMB * 2;   // mb lo
    ushort* wqth   = (ushort*)(ws + o); o += (size_t)EMB * EMB * 2;   // Wq^T hi
    ushort* wqtl   = (ushort*)(ws + o); o += (size_t)EMB * EMB * 2;   // Wq^T lo
    ushort* Pfh    = (ushort*)(ws + o); o += (size_t)MSL * EMB * 2;   // P hi, frag order
    ushort* Pfl    = (ushort*)(ws + o); o += (size_t)MSL * EMB * 2;   // P lo, frag order
    ushort* RTfrag = (ushort*)(ws + o); o += (size_t)EMB * MSL * 2;   // RT, frag order
    float*  cvec   = (float*)(ws + o);  o += (size_t)MSL * 4;

    // 1) merged tiny precomputes (transpose+split Wq, split mb, cvec)
    pre_small<<<576, 256, 0, stream>>>(Wq, wqth, wqtl, mb, mbh, mbl, bq, cvec);

    // 2) both folded-projection GEMMs, fragment-order epilogues
    pre_gemms<<<32, 256, 0, stream>>>(mb, wqth, wqtl, Wo, mbh, mbl, Pfh, Pfl, RTfrag);

    // 3) fused scores + softmax + PV + bias + residual
    //    (64 tokens/block, 34 KiB LDS, 3 blocks/CU, B-frags direct from L2)
    fused_attn<<<TOK / 64, 256, 0, stream>>>(x, Pfh, Pfl, cvec, RTfrag, bo, out);
}

// Round 6
// 355.475 us; speedup vs baseline: 1.0366x; 1.0366x over previous
//
#include <hip/hip_runtime.h>
#include <hip/hip_bf16.h>
#include <stdint.h>

// Problem constants (fixed by reference: B=8, Q=4096, E=1024, M=256)
#define TOK 32768
#define EMB 1024
#define MSL 256

typedef __attribute__((ext_vector_type(8))) short short8;   // 8 bf16 = 4 VGPRs (MFMA A/B frag)
typedef __attribute__((ext_vector_type(4))) float f32x4;    // MFMA C/D frag

// raw barrier: lgkm drain only (publishes ds_writes). No vmcnt drain — the
// fused kernel has NO cross-wave global->LDS dependencies.
#define SBAR() asm volatile("s_waitcnt lgkmcnt(0)\n\ts_barrier" ::: "memory")

__device__ __forceinline__ ushort f2bf(float f) {
    union { float f; uint32_t u; } c; c.f = f;
    uint32_t u = c.u;
    return (ushort)((u + 0x7fffu + ((u >> 16) & 1u)) >> 16);  // RNE
}

// truncation split: f = hi + lo with |f - hi - lo| <= 2^-16 |f|
__device__ __forceinline__ void split2(float f, ushort& h, ushort& l) {
    union { float f; uint32_t u; } c; c.f = f;
    h = (ushort)(c.u >> 16);
    union { uint32_t u; float f; } hv; hv.u = c.u & 0xffff0000u;
    union { float f; uint32_t u; } lc; lc.f = f - hv.f;
    l = (ushort)(lc.u >> 16);
}

__device__ __forceinline__ void async_copy16(const void* gsrc, void* ldst) {
    __builtin_amdgcn_global_load_lds(
        (const __attribute__((address_space(1))) uint32_t*)gsrc,
        (__attribute__((address_space(3))) uint32_t*)ldst,
        16, 0, 0);
}

// Fragment-order index for phase-1 B operands (Ph/Pl), element (m, k):
//   kt=k>>6, kc=(k>>3)&7, ks=kc>>2, lanehi=kc&3, e=k&7, wcj=m>>4, lanelo=m&15
//   idx = (((kt*2+ks)*16 + wcj)*64 + lanehi*16+lanelo)*8 + e
// A wave reading (kt,ks,wcj) loads 64 lanes x 16B contiguous.

// =====================================================================
// pre_small: merged tiny precomputes
// =====================================================================
__global__ __launch_bounds__(256) void pre_small(
    const float* __restrict__ Wq, ushort* __restrict__ wqth, ushort* __restrict__ wqtl,
    const float* __restrict__ mb, ushort* __restrict__ mbh, ushort* __restrict__ mbl,
    const float* __restrict__ bq, float* __restrict__ cvec)
{
    __shared__ float ld[64 * 65];
    const int b = blockIdx.x;
    const int t = threadIdx.x;
    if (b < 256) {
        const int eBase = (b & 15) * 64;
        const int fBase = (b >> 4) * 64;
        #pragma unroll
        for (int r = 0; r < 16; ++r) {
            int row = r * 4 + (t >> 6);      // f within tile
            int col = t & 63;                // e within tile
            ld[row * 65 + col] = Wq[(size_t)(fBase + row) * EMB + eBase + col];
        }
        __syncthreads();
        #pragma unroll
        for (int r = 0; r < 16; ++r) {
            int row = r * 4 + (t >> 6);      // e within tile
            int col = t & 63;                // f within tile
            float v = ld[col * 65 + row];    // = Wq[fBase+col][eBase+row]
            ushort h, l; split2(v, h, l);
            size_t o = (size_t)(eBase + row) * EMB + fBase + col;
            wqth[o] = h; wqtl[o] = l;
        }
    } else if (b < 512) {
        int i = (b - 256) * 256 + t;         // mb: 256*1024/4 float4s
        float4 v = ((const float4*)mb)[i];
        ushort4 h4, l4;
        split2(v.x, h4.x, l4.x); split2(v.y, h4.y, l4.y);
        split2(v.z, h4.z, l4.z); split2(v.w, h4.w, l4.w);
        ((ushort4*)mbh)[i] = h4;
        ((ushort4*)mbl)[i] = l4;
    } else {
        int m = (b - 512) * 4 + (t >> 6);
        int lane = t & 63;
        const float4* mrow = (const float4*)(mb + (size_t)m * EMB);
        const float4* brow = (const float4*)bq;
        float s = 0.f;
        #pragma unroll
        for (int k = 0; k < 4; ++k) {
            float4 a = mrow[lane + k * 64];
            float4 bb = brow[lane + k * 64];
            s += a.x * bb.x + a.y * bb.y + a.z * bb.z + a.w * bb.w;
        }
        #pragma unroll
        for (int off = 32; off; off >>= 1) s += __shfl_xor(s, off, 64);
        if (lane == 0) cvec[m] = s;
    }
}

// =====================================================================
// Split-precision GEMM body (prologue GEMMs).
// MODE 0: P GEMM -> write hi/lo into phase-1 FRAGMENT layout (O1=Pfh, O2=Pfl)
// MODE 1: RT GEMM -> write bf16 into phase-2 fragment layout (O1=RTfrag)
// =====================================================================
template<int MODE>
__device__ __forceinline__ void gemm_body(
    ushort* smem, const float* __restrict__ A,
    const ushort* __restrict__ Bh, const ushort* __restrict__ Bl,
    ushort* __restrict__ O1, ushort* __restrict__ O2,
    int K, int bx, int by)
{
    ushort* sAh = smem;            // [128][64] = 8192 ushorts each
    ushort* sAl = smem + 8192;
    ushort* sBh = smem + 16384;
    ushort* sBl = smem + 24576;

    const int t = threadIdx.x;
    const int lane = t & 63;
    const int wave = t >> 6;
    const int wr = wave >> 1;
    const int wc = wave & 1;
    const int rowBase = by * 128;
    const int colBase = bx * 128;

    const float*  Ab  = A  + (size_t)rowBase * K;
    const ushort* Bhb = Bh + (size_t)colBase * K;
    const ushort* Blb = Bl + (size_t)colBase * K;

    const int cg = ((t & 7) ^ ((t >> 3) & 7)) << 3;

    f32x4 acc[4][4] = {};

    const int kIters = K >> 6;
    for (int kt = 0; kt < kIters; ++kt) {
        const int k0 = kt << 6;
        __syncthreads();
        #pragma unroll
        for (int r = 0; r < 4; ++r) {
            int row = r * 32 + (t >> 3);
            async_copy16(Bhb + (size_t)row * K + k0 + cg, &sBh[(size_t)(r * 256 + wave * 64) * 8]);
            async_copy16(Blb + (size_t)row * K + k0 + cg, &sBl[(size_t)(r * 256 + wave * 64) * 8]);
        }
        #pragma unroll
        for (int r = 0; r < 4; ++r) {
            int i = r * 256 + t;
            int row = r * 32 + (t >> 3);
            const float* src = Ab + (size_t)row * K + k0 + cg;
            float4 f0 = *(const float4*)src;
            float4 f1 = *(const float4*)(src + 4);
            short8 hv, lv; ushort h, l;
            split2(f0.x, h, l); hv[0] = (short)h; lv[0] = (short)l;
            split2(f0.y, h, l); hv[1] = (short)h; lv[1] = (short)l;
            split2(f0.z, h, l); hv[2] = (short)h; lv[2] = (short)l;
            split2(f0.w, h, l); hv[3] = (short)h; lv[3] = (short)l;
            split2(f1.x, h, l); hv[4] = (short)h; lv[4] = (short)l;
            split2(f1.y, h, l); hv[5] = (short)h; lv[5] = (short)l;
            split2(f1.z, h, l); hv[6] = (short)h; lv[6] = (short)l;
            split2(f1.w, h, l); hv[7] = (short)h; lv[7] = (short)l;
            *(short8*)&sAh[(size_t)i * 8] = hv;
            *(short8*)&sAl[(size_t)i * 8] = lv;
        }
        __syncthreads();

        #pragma unroll
        for (int ks = 0; ks < 2; ++ks) {
            const int kc = ks * 4 + (lane >> 4);
            short8 ah[4], al[4], bh[4], bl[4];
            #pragma unroll
            for (int i2 = 0; i2 < 4; ++i2) {
                int row = wr * 64 + i2 * 16 + (lane & 15);
                int off = row * 64 + ((kc ^ (row & 7)) << 3);
                ah[i2] = *(const short8*)&sAh[off];
                al[i2] = *(const short8*)&sAl[off];
            }
            #pragma unroll
            for (int j = 0; j < 4; ++j) {
                int row = wc * 64 + j * 16 + (lane & 15);
                int off = row * 64 + ((kc ^ (row & 7)) << 3);
                bh[j] = *(const short8*)&sBh[off];
                bl[j] = *(const short8*)&sBl[off];
            }
            #pragma unroll
            for (int i2 = 0; i2 < 4; ++i2)
                #pragma unroll
                for (int j = 0; j < 4; ++j) {
                    acc[i2][j] = __builtin_amdgcn_mfma_f32_16x16x32_bf16(ah[i2], bh[j], acc[i2][j], 0, 0, 0);
                    acc[i2][j] = __builtin_amdgcn_mfma_f32_16x16x32_bf16(ah[i2], bl[j], acc[i2][j], 0, 0, 0);
                    acc[i2][j] = __builtin_amdgcn_mfma_f32_16x16x32_bf16(al[i2], bh[j], acc[i2][j], 0, 0, 0);
                }
        }
    }

    // epilogue: C/D layout col=lane&15, row=(lane>>4)*4+reg  [verified m89/m91]
    #pragma unroll
    for (int i2 = 0; i2 < 4; ++i2) {
        #pragma unroll
        for (int j = 0; j < 4; ++j) {
            const int col = colBase + wc * 64 + j * 16 + (lane & 15);
            #pragma unroll
            for (int r = 0; r < 4; ++r) {
                const int row = rowBase + wr * 64 + i2 * 16 + ((lane >> 4) << 2) + r;
                float v = acc[i2][j][r];
                if (MODE == 0) {
                    // (m=row, k=col) -> phase-1 fragment index
                    int ktx = col >> 6, kcc = (col >> 3) & 7;
                    int ksx = kcc >> 2, lh = kcc & 3, e = col & 7;
                    int wcj = row >> 4, ll = row & 15;
                    size_t idx = (((size_t)(ktx * 2 + ksx) * 16 + wcj) * 64 + lh * 16 + ll) * 8 + e;
                    ushort h, l; split2(v, h, l);
                    O1[idx] = h;
                    O2[idx] = l;
                } else {
                    // (f=row, m=col) -> phase-2 fragment index
                    int fc = row >> 6, jj = (row & 63) >> 4, lanelo = row & 15;
                    int cc = col >> 3, ksx = cc >> 2, lanehi = cc & 3, e = col & 7;
                    size_t idx = ((((size_t)fc * 8 + ksx) * 4 + jj) * 64 + lanehi * 16 + lanelo) * 8 + e;
                    O1[idx] = f2bf(v);
                }
            }
        }
    }
}

// pre_gemms: blocks 0..15 -> P frag hi/lo; blocks 16..31 -> RT frag layout
__global__ __launch_bounds__(256) void pre_gemms(
    const float* __restrict__ mb, const ushort* __restrict__ wqth, const ushort* __restrict__ wqtl,
    const float* __restrict__ Wo, const ushort* __restrict__ mbh, const ushort* __restrict__ mbl,
    ushort* __restrict__ Pfh, ushort* __restrict__ Pfl, ushort* __restrict__ RTfrag)
{
    __shared__ ushort smem[32768];   // 64 KiB
    const int b = blockIdx.x;
    if (b < 16) {
        // P[m,e] = sum_f mb[m,f] * WqT[e,f] ; grid (8 e-cols x 2 m-rows)
        gemm_body<0>(smem, mb, wqth, wqtl, Pfh, Pfl, EMB, b & 7, b >> 3);
    } else {
        // RT[f,m] = sum_e Wo[f,e] * mb[m,e] ; grid (2 m-cols x 8 f-rows)
        const int id = b - 16;
        gemm_body<1>(smem, Wo, mbh, mbl, RTfrag, nullptr, EMB, id & 1, id >> 1);
    }
}

// =====================================================================
// Fused: scores + softmax + PV + bias + residual.
// 64 tokens/block, 512 threads = 8 waves, grid 512 -> 2 blocks/CU =
// 16 waves/CU = 4 waves/SIMD (vs 8 waves/CU in ALL previous rounds --
// the measured invariant behind the 133-151us plateau). VGPR capped at
// 128 via __launch_bounds__(512,4) so 4 waves/SIMD are resident.
//
// Phase 1: scores[64x256] = x @ (Ph+Pl)^T + c. Wave tile 64 rows x 32 m
// (8 col-groups, ZERO B duplication -> block reads exactly 2MB of P from
// L2). B-frags direct from global in fragment order; only x in LDS
// (hi/lo split, double-buffered, one lgkm-only barrier per K-step).
// Softmax: 16-lane shfl groups + 8-way cross-wave combine (4 KB LDS).
// Phase 2: out = w @ RT^T + bo + x. Barrier-free; wave tile 16 rows x
// 32 f, af[8] in regs, RT frags from L2.
//
// LDS map (ushort idx): x dbuf 0..16383 (buf kt&1 at (kt&1)*8192:
//   Ah +0, Al +4096); sW[64][256] overlays 0..16383 (post-phase-1);
//   redM floats 16384..17407, redS 17408..18431.
// =====================================================================
__global__ __launch_bounds__(512, 4) void fused_attn(
    const float* __restrict__ x, const ushort* __restrict__ Pfh,
    const ushort* __restrict__ Pfl, const float* __restrict__ cvec,
    const ushort* __restrict__ RTfrag, const float* __restrict__ bo,
    float* __restrict__ out)
{
    __shared__ ushort smem[18432];            // 36 KiB
    ushort* sW  = smem;                       // [64][256] swizzled (phase 2)
    float*  redM = (float*)&smem[16384];      // [8][64] partial max
    float*  redS = (float*)&smem[17408];      // [8][64] partial sum

    const int t = threadIdx.x;
    const int lane = t & 63;
    const int wave = t >> 6;                  // 0..7
    const int wc = wave;                      // phase-1 col group (32 m each)
    const int rowBase = blockIdx.x * 64;

    const float* Ab = x + (size_t)rowBase * EMB;
    const int cg = ((t & 7) ^ ((t >> 3) & 7)) << 3;

    f32x4 acc[4][2] = {};
    float4 xr[2];

    // prefetch x slice for kt into registers (2 float4 = 8 floats/thread)
    auto loadX = [&](int kt) {
        const int k0 = kt << 6;
        const float* src = Ab + (size_t)(t >> 3) * EMB + k0 + cg;
        xr[0] = *(const float4*)src;
        xr[1] = *(const float4*)(src + 4);
    };

    loadX(0);

    // ---------------- phase 1: scores ----------------
    for (int kt = 0; kt < 16; ++kt) {
        ushort* bufAh = smem + (kt & 1) * 8192;
        ushort* bufAl = bufAh + 4096;
        // split x(kt) regs -> LDS (hi/lo); 512 threads cover 64x64
        {
            short8 hv, lv; ushort h, l;
            split2(xr[0].x, h, l); hv[0] = (short)h; lv[0] = (short)l;
            split2(xr[0].y, h, l); hv[1] = (short)h; lv[1] = (short)l;
            split2(xr[0].z, h, l); hv[2] = (short)h; lv[2] = (short)l;
            split2(xr[0].w, h, l); hv[3] = (short)h; lv[3] = (short)l;
            split2(xr[1].x, h, l); hv[4] = (short)h; lv[4] = (short)l;
            split2(xr[1].y, h, l); hv[5] = (short)h; lv[5] = (short)l;
            split2(xr[1].z, h, l); hv[6] = (short)h; lv[6] = (short)l;
            split2(xr[1].w, h, l); hv[7] = (short)h; lv[7] = (short)l;
            *(short8*)&bufAh[(size_t)t * 8] = hv;
            *(short8*)&bufAl[(size_t)t * 8] = lv;
        }
        if (kt < 15) loadX(kt + 1);   // prefetch next slice (covers HBM latency)
        SBAR();   // publish this buf; prev buf's reads fenced by previous SBAR

        #pragma unroll
        for (int ks = 0; ks < 2; ++ks) {
            const int kc = ks * 4 + (lane >> 4);
            short8 bh[2], bl[2];
            #pragma unroll
            for (int j = 0; j < 2; ++j) {
                // B frags straight from global (fragment-order, L2-resident)
                size_t boff = ((size_t)((kt * 2 + ks) * 16 + wc * 2 + j) * 64 + lane) * 8;
                bh[j] = *(const short8*)&Pfh[boff];
                bl[j] = *(const short8*)&Pfl[boff];
            }
            #pragma unroll
            for (int i2 = 0; i2 < 4; ++i2) {
                int row = i2 * 16 + (lane & 15);
                int off = row * 64 + ((kc ^ (row & 7)) << 3);
                short8 ah = *(const short8*)&bufAh[off];
                short8 al = *(const short8*)&bufAl[off];
                #pragma unroll
                for (int j = 0; j < 2; ++j) {
                    acc[i2][j] = __builtin_amdgcn_mfma_f32_16x16x32_bf16(ah, bh[j], acc[i2][j], 0, 0, 0);
                    acc[i2][j] = __builtin_amdgcn_mfma_f32_16x16x32_bf16(ah, bl[j], acc[i2][j], 0, 0, 0);
                    acc[i2][j] = __builtin_amdgcn_mfma_f32_16x16x32_bf16(al, bh[j], acc[i2][j], 0, 0, 0);
                }
            }
        }
    }

    // ---------------- softmax (64 rows; cols split over 8 waves) ------------
    {
        float cj[2];
        #pragma unroll
        for (int j = 0; j < 2; ++j) cj[j] = cvec[wc * 32 + j * 16 + (lane & 15)];
        #pragma unroll
        for (int i2 = 0; i2 < 4; ++i2)
            #pragma unroll
            for (int j = 0; j < 2; ++j)
                #pragma unroll
                for (int r = 0; r < 4; ++r) acc[i2][j][r] += cj[j];
    }
    float pmax[4][4];
    #pragma unroll
    for (int i2 = 0; i2 < 4; ++i2)
        #pragma unroll
        for (int r = 0; r < 4; ++r) {
            float m0 = fmaxf(acc[i2][0][r], acc[i2][1][r]);
            #pragma unroll
            for (int off = 8; off; off >>= 1) m0 = fmaxf(m0, __shfl_xor(m0, off, 64));
            pmax[i2][r] = m0;
        }
    __syncthreads();   // bar A: all phase-1 LDS reads complete
    if ((lane & 15) == 0) {
        #pragma unroll
        for (int i2 = 0; i2 < 4; ++i2)
            #pragma unroll
            for (int r = 0; r < 4; ++r)
                redM[wc * 64 + i2 * 16 + ((lane >> 4) << 2) + r] = pmax[i2][r];
    }
    __syncthreads();   // bar B
    {
        float psum[4][4];
        #pragma unroll
        for (int i2 = 0; i2 < 4; ++i2)
            #pragma unroll
            for (int r = 0; r < 4; ++r) {
                int R = i2 * 16 + ((lane >> 4) << 2) + r;
                float mx = redM[R];
                #pragma unroll
                for (int w2 = 1; w2 < 8; ++w2) mx = fmaxf(mx, redM[w2 * 64 + R]);
                float s = 0.f;
                #pragma unroll
                for (int j = 0; j < 2; ++j) {
                    float e = __expf(acc[i2][j][r] - mx);
                    acc[i2][j][r] = e;
                    s += e;
                }
                #pragma unroll
                for (int off = 8; off; off >>= 1) s += __shfl_xor(s, off, 64);
                psum[i2][r] = s;
            }
        if ((lane & 15) == 0) {
            #pragma unroll
            for (int i2 = 0; i2 < 4; ++i2)
                #pragma unroll
                for (int r = 0; r < 4; ++r)
                    redS[wc * 64 + i2 * 16 + ((lane >> 4) << 2) + r] = psum[i2][r];
        }
    }
    __syncthreads();   // bar C
    // normalize -> bf16 weights -> swizzled sW[64][256]
    #pragma unroll
    for (int i2 = 0; i2 < 4; ++i2)
        #pragma unroll
        for (int r = 0; r < 4; ++r) {
            int R = i2 * 16 + ((lane >> 4) << 2) + r;
            float tot = redS[R];
            #pragma unroll
            for (int w2 = 1; w2 < 8; ++w2) tot += redS[w2 * 64 + R];
            float inv = 1.0f / tot;
            #pragma unroll
            for (int j = 0; j < 2; ++j) {
                int col = wc * 32 + j * 16 + (lane & 15);
                int cc = col >> 3;
                int slot = (cc & 24) | ((cc & 7) ^ (R & 7));
                sW[R * 256 + slot * 8 + (lane & 7)] = f2bf(acc[i2][j][r] * inv);
            }
        }
    __syncthreads();   // bar D: sW complete

    // ---------------- phase 2: out = w @ RT^T + bo + x (barrier-free) -------
    const int wr2 = wave >> 1;    // 0..3 : token rows wr2*16
    const int wc2 = wave & 1;     // 0..1 : f cols wc2*32 within a 64-f chunk

    short8 af[8];
    {
        int R = wr2 * 16 + (lane & 15);
        #pragma unroll
        for (int ks = 0; ks < 8; ++ks) {
            int cc = ks * 4 + (lane >> 4);
            int slot = (cc & 24) | ((cc & 7) ^ (R & 7));
            af[ks] = *(const short8*)&sW[R * 256 + slot * 8];
        }
    }

    for (int fc = 0; fc < 16; ++fc) {
        f32x4 acc2[2] = {};
        #pragma unroll
        for (int ks = 0; ks < 8; ++ks) {
            short8 b[2];
            #pragma unroll
            for (int j = 0; j < 2; ++j) {
                int jj = wc2 * 2 + j;
                b[j] = *(const short8*)&RTfrag[((((size_t)fc * 8 + ks) * 4 + jj) * 64 + lane) * 8];
            }
            #pragma unroll
            for (int j = 0; j < 2; ++j)
                acc2[j] = __builtin_amdgcn_mfma_f32_16x16x32_bf16(af[ks], b[j], acc2[j], 0, 0, 0);
        }
        // epilogue: + bias + residual, fp32 store (x rows L2/L3-hot from ph1)
        #pragma unroll
        for (int j = 0; j < 2; ++j) {
            int col = fc * 64 + wc2 * 32 + j * 16 + (lane & 15);
            float bcol = bo[col];
            #pragma unroll
            for (int r = 0; r < 4; ++r) {
                int row = rowBase + wr2 * 16 + ((lane >> 4) << 2) + r;
                out[(size_t)row * EMB + col] =
                    acc2[j][r] + bcol + x[(size_t)row * EMB + col];
            }
        }
    }
}

extern "C" void kernel_launch(void* const* d_in, const int* in_sizes, int n_in,
                              void* d_out, int out_size, void* d_ws, size_t ws_size,
                              hipStream_t stream) {
    const float* x  = (const float*)d_in[0];   // [TOK, EMB]
    const float* mb = (const float*)d_in[1];   // [MSL, EMB]
    const float* Wq = (const float*)d_in[2];   // [EMB, EMB]
    const float* bq = (const float*)d_in[3];   // [EMB]
    const float* Wo = (const float*)d_in[4];   // [EMB, EMB]
    const float* bo = (const float*)d_in[5];   // [EMB]
    float* out = (float*)d_out;                // [TOK, EMB]

    // workspace layout (~6.5 MB), no atomics -> no zeroing
    char* ws = (char*)d_ws;
    size_t o = 0;
    ushort* mbh    = (ushort*)(ws + o); o += (size_t)MSL * EMB * 2;   // mb hi
    ushort* mbl    = (ushort*)(ws + o); o += (size_t)MSL * EMB * 2;   // mb lo
    ushort* wqth   = (ushort*)(ws + o); o += (size_t)EMB * EMB * 2;   // Wq^T hi
    ushort* wqtl   = (ushort*)(ws + o); o += (size_t)EMB * EMB * 2;   // Wq^T lo
    ushort* Pfh    = (ushort*)(ws + o); o += (size_t)MSL * EMB * 2;   // P hi, frag order
    ushort* Pfl    = (ushort*)(ws + o); o += (size_t)MSL * EMB * 2;   // P lo, frag order
    ushort* RTfrag = (ushort*)(ws + o); o += (size_t)EMB * MSL * 2;   // RT, frag order
    float*  cvec   = (float*)(ws + o);  o += (size_t)MSL * 4;

    // 1) merged tiny precomputes (transpose+split Wq, split mb, cvec)
    pre_small<<<576, 256, 0, stream>>>(Wq, wqth, wqtl, mb, mbh, mbl, bq, cvec);

    // 2) both folded-projection GEMMs, fragment-order epilogues
    pre_gemms<<<32, 256, 0, stream>>>(mb, wqth, wqtl, Wo, mbh, mbl, Pfh, Pfl, RTfrag);

    // 3) fused scores + softmax + PV + bias + residual
    //    (64 tokens/block, 512 threads, grid 512 -> 16 waves/CU)
    fused_attn<<<TOK / 64, 512, 0, stream>>>(x, Pfh, Pfl, cvec, RTfrag, bo, out);
}